// Round 6
// baseline (94.618 us; speedup 1.0000x reference)
//
#include <hip/hip_runtime.h>

// GMLoss: bidirectional chamfer min + Geman-McClure penalty (MU=1).
// srcs, tgts: [B=8, D=3, N=4096] fp32. Output: scalar fp32.
//
// R24: single-pass bidirectional chamfer, OCCUPANCY-DOUBLED.
// Ladder of the single-pass arc:
//  - R19/R20: in-loop col shuffles + full unroll -> 3.1KB/thread scratch
//    spill (600MB traffic, 245us).
//  - R22: #pragma unroll 1 -> spill gone, 88.7us total.
//  - R23: shuffle-free inner loop (per-quad partials to LDS, fire-and-
//    forget) -> 82.5us. Delta profile shows loop is LATENCY-serialized:
//    removing ~2us theoretical shuffle cost bought 6.3us real. Only
//    2 waves/SIMD (grid 512 = exactly 2 blocks/CU; LDS 66.6KB caps too).
//  - R24: 2x TLP. 1024 blocks x 32 rows; sColQ shrunk to a wave-private
//    16-tile ring (4KB/wave, flushed to cpart every 4 trips -- col values
//    are final in their u-step, no cross-trip accumulation, no barrier);
//    LDS 66.6 -> ~17.5KB; __launch_bounds__(256,4) -> 4 blocks/CU
//    = 4 waves/SIMD hiding the same per-trip latency chain.
//
// Invariants (counter-evidenced, 24 rounds):
//  - #pragma unroll 1 on the i-loop; bound MFMA live ranges (R19/R20).
//  - NO cross-lane DS ops inside the MFMA loop (R22->R23: -6.3us).
//  - NO device-scope fences or bulk atomics in hot kernels (R7/R9).
//  - fp32 -> K=13 hi/lo bf16 packing, 16x16x32 MFMA with K-replication
//    (quads 2,3 re-read bytes 0..31 -> D=2P, halve after min).
//  - depth-4 register prefetch ring over B tiles.
// Single-pass: distance matrix ONCE per batch; row-min (per-src) in regs,
// col-min (per-tgt) per-quad partials -> LDS ring -> min4 -> cpart
// [b][stripe=128][4096] (16MB, written-once), stripe-min-reduced by
// colreduce. b = blk&7 pins each batch's Bpack + cpart to one XCD's L2.
// Accuracy: K=13 pack drops only lo.lo (~1e-5 << 1.26e-3); absmax 0.0 on
// R19/R20/R22/R23.
//   A k: [-2sh(3), -2sl(3), -2sh(3), s2h, s2l, 1, 1, 0,0,0]
//   B k: [ th(3),   th(3),   tl(3),  1, 1, t2h, t2l, 0,0,0]
// 16x16x32 layouts (m89/m91): A[m=lane&15][k=(lane>>4)*8+j], B same
// (n=lane&15); D: col=lane&15, row=(lane>>4)*4+reg (quad q holds rows
// q*4..q*4+3 of each 16-row tile).
// Budget: ~43us harness d_ws re-poison (268MB fill, timed) + kernels.

#define NPTS 4096
#define NB   8

typedef __attribute__((ext_vector_type(8))) short bf16x8;
typedef __attribute__((ext_vector_type(4))) float floatx4;

// ws layout: Apack (1MB), Bpack (1MB), colpart 16MB [8][128][4096], bsum
#define OFF_APACK 0u
#define OFF_BPACK (1u << 20)
#define OFF_CPART (2u << 20)
#define OFF_BSUM  (18u << 20)

union V16 { int4 i; bf16x8 h; };

__device__ __forceinline__ unsigned short f2bf(float f) {
    unsigned u = __float_as_uint(f);
    u += 0x7FFFu + ((u >> 16) & 1u);       // RNE
    return (unsigned short)(u >> 16);
}
__device__ __forceinline__ float bf2f(unsigned short h) {
    return __uint_as_float(((unsigned)h) << 16);
}
__device__ __forceinline__ int pk(unsigned short lo, unsigned short hi) {
    return (int)((unsigned)lo | ((unsigned)hi << 16));
}

// ---------------- Kernel 1: pack A-style(srcs) + B-style(tgts) -------------
__device__ __forceinline__ void pack_A(const float* __restrict__ cloud,
                                       int b, int j, int gid,
                                       char* __restrict__ apack) {
    const unsigned short ONE = 0x3F80;
    const float* p = cloud + b * 3 * NPTS;
    const float x = p[j], y = p[NPTS + j], z = p[2 * NPTS + j];
    const unsigned short hx = f2bf(x), hy = f2bf(y), hz = f2bf(z);
    const unsigned short a0 = f2bf(-2.0f * bf2f(hx));
    const unsigned short a1 = f2bf(-2.0f * bf2f(hy));
    const unsigned short a2 = f2bf(-2.0f * bf2f(hz));
    const unsigned short m0 = f2bf(-2.0f * (x - bf2f(hx)));
    const unsigned short m1 = f2bf(-2.0f * (y - bf2f(hy)));
    const unsigned short m2 = f2bf(-2.0f * (z - bf2f(hz)));
    const float n2 = fmaf(z, z, fmaf(y, y, x * x));
    const unsigned short n2h = f2bf(n2);
    const unsigned short n2l = f2bf(n2 - bf2f(n2h));
    int4* Ap = (int4*)(apack + (size_t)gid * 32);
    Ap[0] = make_int4(pk(a0, a1), pk(a2, m0), pk(m1, m2), pk(a0, a1));
    Ap[1] = make_int4(pk(a2, n2h), pk(n2l, ONE), pk(ONE, 0), 0);
}

__device__ __forceinline__ void pack_B(const float* __restrict__ cloud,
                                       int b, int j, int gid,
                                       char* __restrict__ bpack) {
    const unsigned short ONE = 0x3F80;
    const float* p = cloud + b * 3 * NPTS;
    const float x = p[j], y = p[NPTS + j], z = p[2 * NPTS + j];
    const unsigned short hx = f2bf(x), hy = f2bf(y), hz = f2bf(z);
    const unsigned short lx = f2bf(x - bf2f(hx));
    const unsigned short ly = f2bf(y - bf2f(hy));
    const unsigned short lz = f2bf(z - bf2f(hz));
    const float n2 = fmaf(z, z, fmaf(y, y, x * x));
    const unsigned short n2h = f2bf(n2);
    const unsigned short n2l = f2bf(n2 - bf2f(n2h));
    int4* Bp = (int4*)(bpack + (size_t)gid * 32);
    Bp[0] = make_int4(pk(hx, hy), pk(hz, hx), pk(hy, hz), pk(lx, ly));
    Bp[1] = make_int4(pk(lz, ONE), pk(ONE, n2h), pk(n2l, 0), 0);
}

__global__ __launch_bounds__(256)
void transform_kernel(const float* __restrict__ srcs,
                      const float* __restrict__ tgts,
                      char* __restrict__ ws) {
    const int gid = blockIdx.x * 256 + threadIdx.x;   // 0..32767 = b*4096+j
    const int b = gid >> 12, j = gid & 4095;
    pack_A(srcs, b, j, gid, ws + OFF_APACK);
    pack_B(tgts, b, j, gid, ws + OFF_BPACK);
}

// ------- Kernel 2: single-pass bidirectional MFMA chamfer (32 rows) -------
__global__ __launch_bounds__(256, 4)
void chamfer_kernel(char* __restrict__ ws) {
    const int blk    = blockIdx.x;        // 0..1023
    const int b      = blk & 7;           // XCD-pinned batch
    const int stripe = blk >> 3;          // 0..127, 32 src rows each
    const int tid    = threadIdx.x;
    const int wave   = tid >> 6;          // 0..3
    const int lane   = tid & 63;
    const int l15    = lane & 15;
    const int quad   = lane >> 4;         // k-half = (quad&1)*16 bytes

    const char* Ap = ws + OFF_APACK;
    const char* Bp = ws + OFF_BPACK;

    // wave-private 16-tile col-partial ring: [wave][(tile&15)*64+l15*4+quad]
    __shared__ __align__(16) float sColQ[4][1024];   // 16KB total
    __shared__ float sRow[4][32];

    // 2 row-tiles of 16 rows; quads 2,3 replicate quads 0,1 -> D = 2P.
    V16 av[2];
#pragma unroll
    for (int rt = 0; rt < 2; rt++)
        av[rt].i = *(const int4*)(Ap +
            (size_t)(b * NPTS + stripe * 32 + rt * 16 + l15) * 32 + (quad & 1) * 16);

    floatx4 rmin[2];
#pragma unroll
    for (int rt = 0; rt < 2; rt++)
        rmin[rt] = (floatx4){3.0e38f, 3.0e38f, 3.0e38f, 3.0e38f};
    const floatx4 zero = {0.0f, 0.0f, 0.0f, 0.0f};

    const int ct0 = wave * 64;            // 64 col-tiles (of 16 pts) per wave
    const char* bbase = Bp + (size_t)(b * NPTS + ct0 * 16 + l15) * 32 + (quad & 1) * 16;
    float* sq = sColQ[wave];
    float* cprow = (float*)(ws + OFF_CPART) +
                   (size_t)(b * 128 + stripe) * NPTS + ct0 * 16;

    // depth-4 register prefetch ring over 64 tiles, 512 B apart; wrap &63
    V16 t0, t1, t2, t3;
    t0.i = *(const int4*)(bbase);
    t1.i = *(const int4*)(bbase + 512);
    t2.i = *(const int4*)(bbase + 1024);
    t3.i = *(const int4*)(bbase + 1536);

    // unroll 1: one ring batch per trip; bounded MFMA live ranges (R19/R20
    // spilled 3KB/thread with the flattened body).
#pragma unroll 1
    for (int i = 0; i < 64; i += 4) {
        V16 n0, n1, n2, n3;
        n0.i = *(const int4*)(bbase + (size_t)((i + 4) & 63) * 512);
        n1.i = *(const int4*)(bbase + (size_t)((i + 5) & 63) * 512);
        n2.i = *(const int4*)(bbase + (size_t)((i + 6) & 63) * 512);
        n3.i = *(const int4*)(bbase + (size_t)((i + 7) & 63) * 512);
#pragma unroll
        for (int u = 0; u < 4; u++) {
            const bf16x8 bf = (u == 0 ? t0.h : u == 1 ? t1.h : u == 2 ? t2.h : t3.h);
            float colq = 3.0e38f;         // min over this quad's 8 rows
#pragma unroll
            for (int rt = 0; rt < 2; rt++) {
                const floatx4 d =
                    __builtin_amdgcn_mfma_f32_16x16x32_bf16(av[rt].h, bf, zero, 0, 0, 0);
#pragma unroll
                for (int r = 0; r < 4; r++)
                    rmin[rt][r] = fminf(rmin[rt][r], d[r]);
                colq = fminf(colq,
                             fminf(fminf(d[0], d[1]), fminf(d[2], d[3])));
            }
            // fire-and-forget per-quad partial into the wave-private ring;
            // word = (tile&15)*64 + l15*4 + quad covers 32 banks exactly 2x
            sq[(((i + u) & 15) * 16 + l15) * 4 + quad] = colq;
        }
        t0 = n0; t1 = n1; t2 = n2; t3 = n3;
        // every 4 trips the 16-tile ring (256 cols) is final: min4 + flush.
        // Wave-private LDS -> no barrier; 4 coalesced 256B stores per wave.
        if ((i & 15) == 12) {
            float* cp = cprow + (i >> 4) * 256;
#pragma unroll
            for (int k2 = 0; k2 < 4; k2++) {
                const float4 v = *(const float4*)&sq[(k2 * 64 + lane) * 4];
                cp[k2 * 64 + lane] = fminf(fminf(v.x, v.y), fminf(v.z, v.w));
            }
        }
    }

    // ---- row side: butterfly min over the 16 col-lanes ----
#pragma unroll
    for (int off = 1; off < 16; off <<= 1) {
#pragma unroll
        for (int rt = 0; rt < 2; rt++)
#pragma unroll
            for (int r = 0; r < 4; r++)
                rmin[rt][r] = fminf(rmin[rt][r], __shfl_xor(rmin[rt][r], off, 64));
    }
    // quad leader holds rows rt*16 + quad*4 + r (32 rows total)
    if (l15 == 0) {
#pragma unroll
        for (int rt = 0; rt < 2; rt++)
#pragma unroll
            for (int r = 0; r < 4; r++)
                sRow[wave][rt * 16 + quad * 4 + r] = rmin[rt][r];
    }
    __syncthreads();
    if (tid < 32) {
        float m = fminf(fminf(sRow[0][tid], sRow[1][tid]),
                        fminf(sRow[2][tid], sRow[3][tid]));
        m = fmaxf(m * 0.5f, 0.0f);        // undo K-replication doubling
        float g = m / (m + 1.0f);         // GM, MU=1
#pragma unroll
        for (int off = 1; off < 32; off <<= 1)
            g += __shfl_xor(g, off, 64);
        if (tid == 0)
            ((float*)(ws + OFF_BSUM))[blk] = g;   // plain store
    }
}

// ---- Kernel 3: stripe-min reduce of col partials + GM partial sums -------
__global__ __launch_bounds__(256)
void colreduce_kernel(char* __restrict__ ws) {
    const int blk = blockIdx.x;           // 0..127
    const int b   = blk & 7;              // match chamfer's XCD pinning
    const int cc  = blk >> 3;             // 0..15, 256-col chunk
    const int tid = threadIdx.x;
    const float* cp = (const float*)(ws + OFF_CPART) +
                      (size_t)b * 128 * NPTS + cc * 256 + tid;
    float m0 = 3.0e38f, m1 = 3.0e38f, m2 = 3.0e38f, m3 = 3.0e38f;
    float m4 = 3.0e38f, m5 = 3.0e38f, m6 = 3.0e38f, m7 = 3.0e38f;
#pragma unroll 2
    for (int s = 0; s < 128; s += 8) {    // 8 chains for load ILP
        m0 = fminf(m0, cp[(size_t)(s + 0) * NPTS]);
        m1 = fminf(m1, cp[(size_t)(s + 1) * NPTS]);
        m2 = fminf(m2, cp[(size_t)(s + 2) * NPTS]);
        m3 = fminf(m3, cp[(size_t)(s + 3) * NPTS]);
        m4 = fminf(m4, cp[(size_t)(s + 4) * NPTS]);
        m5 = fminf(m5, cp[(size_t)(s + 5) * NPTS]);
        m6 = fminf(m6, cp[(size_t)(s + 6) * NPTS]);
        m7 = fminf(m7, cp[(size_t)(s + 7) * NPTS]);
    }
    float m = fminf(fminf(fminf(m0, m1), fminf(m2, m3)),
                    fminf(fminf(m4, m5), fminf(m6, m7)));
    m = fmaxf(m * 0.5f, 0.0f);            // undo K-replication doubling
    float g = m / (m + 1.0f);             // GM, MU=1
#pragma unroll
    for (int off = 1; off < 64; off <<= 1)
        g += __shfl_xor(g, off, 64);
    __shared__ float sp[4];
    if ((tid & 63) == 0) sp[tid >> 6] = g;
    __syncthreads();
    if (tid == 0)
        ((float*)(ws + OFF_BSUM))[1024 + blk] = sp[0] + sp[1] + sp[2] + sp[3];
}

// ---------------- Kernel 4: single-block finish ----------------
__global__ __launch_bounds__(256)
void final_kernel(const char* __restrict__ ws, float* __restrict__ out) {
    const float* bsum = (const float*)(ws + OFF_BSUM);
    const int tid = threadIdx.x;
    float g = bsum[tid] + bsum[tid + 256] +           // row-side 1024
              bsum[tid + 512] + bsum[tid + 768];
    if (tid < 128) g += bsum[1024 + tid];             // col-side 128
#pragma unroll
    for (int off = 1; off < 64; off <<= 1)
        g += __shfl_xor(g, off, 64);
    __shared__ float sp[4];
    if ((tid & 63) == 0) sp[tid >> 6] = g;
    __syncthreads();
    if (tid == 0)
        out[0] = (sp[0] + sp[1] + sp[2] + sp[3]) * (1.0f / (NB * NPTS));
}

extern "C" void kernel_launch(void* const* d_in, const int* in_sizes, int n_in,
                              void* d_out, int out_size, void* d_ws, size_t ws_size,
                              hipStream_t stream) {
    const float* srcs = (const float*)d_in[0];
    const float* tgts = (const float*)d_in[1];
    float* out = (float*)d_out;
    char* ws = (char*)d_ws;

    transform_kernel<<<dim3(128), dim3(256), 0, stream>>>(srcs, tgts, ws);
    chamfer_kernel<<<dim3(1024), dim3(256), 0, stream>>>(ws);
    colreduce_kernel<<<dim3(128), dim3(256), 0, stream>>>(ws);
    final_kernel<<<dim3(1), dim3(256), 0, stream>>>(ws, out);
}

// Round 7
// 79.831 us; speedup vs baseline: 1.1852x; 1.1852x over previous
//
#include <hip/hip_runtime.h>

// GMLoss: bidirectional chamfer min + Geman-McClure penalty (MU=1).
// srcs, tgts: [B=8, D=3, N=4096] fp32. Output: scalar fp32.
//
// R25: R14 two-pass structure (best measured: 72.6us) MINUS the finish
// dispatch. Ladder evidence for dispatch-count as the lever:
//   R14 3 kernels: rest-after-fill = 32.2us | R23 4 kernels: 39.1us
//   (+1 dispatch ~= +7us: launch + full-grid drain). Single-pass halved
//   MFMA work but re-added a dispatch (colreduce) -> net zero before its
//   other regressions (R19-R24 all >= 82.5us). So: keep the PROVEN R14
//   chamfer loop byte-for-byte, cut dispatches 4 -> 3:
//    - transform thread 0 zeroes out[0] (kernel-boundary release makes it
//      visible device-wide to the next kernel);
//    - each chamfer block's reducer lane does ONE device-scope
//      atomicAdd(out, partial/32768). 1024 atomics total at block-end --
//      NOT R7's 2M hot-loop RMWs, and no fences (R9). absmax moves off
//      0.0 by atomic-order ulp jitter only (<< 1.26e-3).
//    - finish kernel deleted.
//
// Structure (inherited from R14, 18+7 rounds of evidence):
//  - transform: fp32 -> K=13 hi/lo bf16 MFMA packing for both clouds
//    (A-style + B-style), 1 point/thread.
//  - chamfer: 16x16x32 bf16 MFMA, K-replication (quads 2,3 re-read bytes
//    0..31 -> D=2P, halve after min), 64 query rows/block, depth-4 register
//    prefetch ring, XCD swizzle group=blk&15, pure-rmin loop (NO col path,
//    NO LDS in loop, full 16-iter unroll -- short consumer chains don't
//    spill; R19/R20 showed multi-consumer chains + full unroll DO).
// Hard invariants (counter-evidenced):
//  - NO device-scope fences or BULK atomics in hot loops (R7: 2M atomicMin
//    -> 478MB RMW, 263us; R9: per-block threadfence -> 70us floor).
//  - __launch_bounds__(256,2) on chamfer (VGPR 128; grid 1024 = 4 blk/CU).
//  - Neutral around this structure: 32x32x16 shape, depth-8 ring, in-place
//    ring + min3, swizzle granularity (R15-R17).
// Accuracy: K=13 pack drops only lo.lo (~1e-5 << 1.26e-3 threshold).
//   A k: [-2sh(3), -2sl(3), -2sh(3), s2h, s2l, 1, 1, 0,0,0]
//   B k: [ th(3),   th(3),   tl(3),  1, 1, t2h, t2l, 0,0,0]
// 16x16x32 layouts (m89/m91): A[m=lane&15][k=(lane>>4)*8+j], B same
// (n=lane&15); D: col=lane&15, row=(lane>>4)*4+reg.
// Budget: ~40-48us harness d_ws re-poison (268MB fill, timed, DRIFTS) +
// 2 kernel dispatches. Judge rounds by (total - fill).

#define NPTS 4096
#define NB   8

typedef __attribute__((ext_vector_type(8))) short bf16x8;
typedef __attribute__((ext_vector_type(4))) float floatx4;

// ws layout: Apack[srcs], Apack[tgts], Bpack[srcs], Bpack[tgts]
#define OFF_APACK_S 0u
#define OFF_APACK_T (1u << 20)
#define OFF_BPACK_S (2u << 20)
#define OFF_BPACK_T (3u << 20)

union V16 { int4 i; bf16x8 h; };

__device__ __forceinline__ unsigned short f2bf(float f) {
    unsigned u = __float_as_uint(f);
    u += 0x7FFFu + ((u >> 16) & 1u);       // RNE
    return (unsigned short)(u >> 16);
}
__device__ __forceinline__ float bf2f(unsigned short h) {
    return __uint_as_float(((unsigned)h) << 16);
}
__device__ __forceinline__ int pk(unsigned short lo, unsigned short hi) {
    return (int)((unsigned)lo | ((unsigned)hi << 16));
}

// ---------------- Kernel 1: pack A-style + B-style, 1 point/thread --------
__device__ __forceinline__ void pack_point(const float* __restrict__ cloud,
                                           int b, int j, int gid,
                                           char* __restrict__ apack,
                                           char* __restrict__ bpack) {
    const unsigned short ONE = 0x3F80;
    const float* p = cloud + b * 3 * NPTS;
    const float x = p[j], y = p[NPTS + j], z = p[2 * NPTS + j];
    const unsigned short hx = f2bf(x), hy = f2bf(y), hz = f2bf(z);
    const unsigned short lx = f2bf(x - bf2f(hx));
    const unsigned short ly = f2bf(y - bf2f(hy));
    const unsigned short lz = f2bf(z - bf2f(hz));
    const unsigned short a0 = f2bf(-2.0f * bf2f(hx));
    const unsigned short a1 = f2bf(-2.0f * bf2f(hy));
    const unsigned short a2 = f2bf(-2.0f * bf2f(hz));
    const unsigned short m0 = f2bf(-2.0f * (x - bf2f(hx)));
    const unsigned short m1 = f2bf(-2.0f * (y - bf2f(hy)));
    const unsigned short m2 = f2bf(-2.0f * (z - bf2f(hz)));
    const float n2 = fmaf(z, z, fmaf(y, y, x * x));
    const unsigned short n2h = f2bf(n2);
    const unsigned short n2l = f2bf(n2 - bf2f(n2h));

    int4* Ap = (int4*)(apack + (size_t)gid * 32);
    Ap[0] = make_int4(pk(a0, a1), pk(a2, m0), pk(m1, m2), pk(a0, a1));
    Ap[1] = make_int4(pk(a2, n2h), pk(n2l, ONE), pk(ONE, 0), 0);

    int4* Bp = (int4*)(bpack + (size_t)gid * 32);
    Bp[0] = make_int4(pk(hx, hy), pk(hz, hx), pk(hy, hz), pk(lx, ly));
    Bp[1] = make_int4(pk(lz, ONE), pk(ONE, n2h), pk(n2l, 0), 0);
}

__global__ __launch_bounds__(256)
void transform_kernel(const float* __restrict__ srcs,
                      const float* __restrict__ tgts,
                      char* __restrict__ ws,
                      float* __restrict__ out) {
    const int gid = blockIdx.x * 256 + threadIdx.x;   // 0..65535
    if (gid == 0) out[0] = 0.0f;          // accumulator for chamfer atomics
    const int dir = gid >> 15;
    const int rem = gid & 32767;                      // b*4096 + j
    const int b = rem >> 12, j = rem & 4095;
    if (dir == 0)
        pack_point(srcs, b, j, rem, ws + OFF_APACK_S, ws + OFF_BPACK_S);
    else
        pack_point(tgts, b, j, rem, ws + OFF_APACK_T, ws + OFF_BPACK_T);
}

// ---------------- Kernel 2: row-min MFMA chamfer (16x16x32, 64 rows) ------
__global__ __launch_bounds__(256, 2)
void chamfer_kernel(char* __restrict__ ws, float* __restrict__ out) {
    const int blk    = blockIdx.x;        // 0..1023
    const int group  = blk & 15;          // XCD-aware swizzle
    const int dir    = group >> 3;
    const int b      = group & 7;
    const int stripe = blk >> 4;          // 0..63, 64 query rows each
    const int tid    = threadIdx.x;
    const int wave   = tid >> 6;          // 0..3
    const int lane   = tid & 63;
    const int l15    = lane & 15;
    const int quad   = lane >> 4;         // k-half = (quad&1)*16 bytes

    const char* Ap = ws + (dir == 0 ? OFF_APACK_S : OFF_APACK_T);
    const char* Bp = ws + (dir == 0 ? OFF_BPACK_T : OFF_BPACK_S);

    // 4 row-tiles of 16 rows; quads 2,3 replicate quads 0,1 -> D = 2P.
    V16 av[4];
#pragma unroll
    for (int rt = 0; rt < 4; rt++)
        av[rt].i = *(const int4*)(Ap +
            (size_t)(b * NPTS + stripe * 64 + rt * 16 + l15) * 32 + (quad & 1) * 16);

    floatx4 rmin[4];
#pragma unroll
    for (int rt = 0; rt < 4; rt++)
        rmin[rt] = (floatx4){3.0e38f, 3.0e38f, 3.0e38f, 3.0e38f};
    const floatx4 zero = {0.0f, 0.0f, 0.0f, 0.0f};

    const int ct0 = wave * 64;            // 64 col-tiles (of 16 pts) per wave
    const char* bbase = Bp + (size_t)(b * NPTS + ct0 * 16 + l15) * 32 + (quad & 1) * 16;

    // depth-4 register prefetch ring over 64 tiles, 512 B apart; wrap &63
    V16 t0, t1, t2, t3;
    t0.i = *(const int4*)(bbase);
    t1.i = *(const int4*)(bbase + 512);
    t2.i = *(const int4*)(bbase + 1024);
    t3.i = *(const int4*)(bbase + 1536);

#pragma unroll
    for (int i = 0; i < 64; i += 4) {
        V16 n0, n1, n2, n3;
        n0.i = *(const int4*)(bbase + (size_t)((i + 4) & 63) * 512);
        n1.i = *(const int4*)(bbase + (size_t)((i + 5) & 63) * 512);
        n2.i = *(const int4*)(bbase + (size_t)((i + 6) & 63) * 512);
        n3.i = *(const int4*)(bbase + (size_t)((i + 7) & 63) * 512);
#pragma unroll
        for (int u = 0; u < 4; u++) {
            const bf16x8 bf = (u == 0 ? t0.h : u == 1 ? t1.h : u == 2 ? t2.h : t3.h);
#pragma unroll
            for (int rt = 0; rt < 4; rt++) {
                const floatx4 d =
                    __builtin_amdgcn_mfma_f32_16x16x32_bf16(av[rt].h, bf, zero, 0, 0, 0);
#pragma unroll
                for (int r = 0; r < 4; r++)
                    rmin[rt][r] = fminf(rmin[rt][r], d[r]);
            }
        }
        t0 = n0; t1 = n1; t2 = n2; t3 = n3;
    }

    // ---- butterfly min over the 16 col-lanes ----
#pragma unroll
    for (int off = 1; off < 16; off <<= 1) {
#pragma unroll
        for (int rt = 0; rt < 4; rt++)
#pragma unroll
            for (int r = 0; r < 4; r++)
                rmin[rt][r] = fminf(rmin[rt][r], __shfl_xor(rmin[rt][r], off, 64));
    }
    // quad leader holds rows rt*16 + quad*4 + r
    __shared__ float sRow[4][64];
    if (l15 == 0) {
#pragma unroll
        for (int rt = 0; rt < 4; rt++)
#pragma unroll
            for (int r = 0; r < 4; r++)
                sRow[wave][rt * 16 + quad * 4 + r] = rmin[rt][r];
    }
    __syncthreads();
    if (tid < 64) {
        float m = fminf(fminf(sRow[0][tid], sRow[1][tid]),
                        fminf(sRow[2][tid], sRow[3][tid]));
        m = fmaxf(m * 0.5f, 0.0f);        // undo K-replication doubling
        float g = m / (m + 1.0f);         // GM, MU=1
#pragma unroll
        for (int off = 1; off < 64; off <<= 1)
            g += __shfl_xor(g, off, 64);
        if (tid == 0)                     // ONE device-scope atomic per block
            atomicAdd(out, g * (1.0f / (NB * NPTS)));
    }
}

extern "C" void kernel_launch(void* const* d_in, const int* in_sizes, int n_in,
                              void* d_out, int out_size, void* d_ws, size_t ws_size,
                              hipStream_t stream) {
    const float* srcs = (const float*)d_in[0];
    const float* tgts = (const float*)d_in[1];
    float* out = (float*)d_out;
    char* ws = (char*)d_ws;

    transform_kernel<<<dim3(256), dim3(256), 0, stream>>>(srcs, tgts, ws, out);
    chamfer_kernel<<<dim3(1024), dim3(256), 0, stream>>>(ws, out);
}

// Round 8
// 74.939 us; speedup vs baseline: 1.2626x; 1.0653x over previous
//
#include <hip/hip_runtime.h>

// GMLoss: bidirectional chamfer min + Geman-McClure penalty (MU=1).
// srcs, tgts: [B=8, D=3, N=4096] fp32. Output: scalar fp32.
//
// R26: R14 two-pass chamfer (best loop: 72.6us) + finish kernel FUSED via
// 64-slot two-level atomic reduction. Evidence chain:
//  - R14 (3 dispatches): rest-after-fill 31.9us.
//  - R25 (2 dispatches, 1024 same-address atomicAdd): rest 39.0us.
//    Same-address device atomics serialize at the coherence point
//    (~30cyc each -> ~13us tail) -- ate the dispatch saving.
//  - R26: 64 slots x 128B lines (parallel L2 channels): 16 adds/slot in
//    parallel across slots (~0.2us), then ONE out[0] atomic per slot (64).
//    Per-thread sum->cnt ordering forced by data dependency on the atomic
//    return value (old*0.0f not foldable without fast-math). No fences
//    (R9), all protocol words accessed only by atomics (device-scope, m20).
//
// Structure (R14, 18+8 rounds of evidence):
//  - transform: fp32 -> K=13 hi/lo bf16 MFMA packing, both clouds, A+B
//    styles, 1 point/thread; also zeroes out[0] + 8KB slot region.
//  - chamfer: 16x16x32 bf16 MFMA, K-replication (quads 2,3 re-read bytes
//    0..31 -> D=2P, halve after min), 64 query rows/block, depth-4 register
//    prefetch ring, XCD swizzle group=blk&15, pure-rmin loop (no col path,
//    no in-loop LDS/global stores, full unroll -- short consumer chains
//    don't spill; R19/R20 multi-consumer chains DID: 600MB scratch).
// Hard invariants (counter-evidenced):
//  - NO device-scope fences or bulk/hot-loop atomics (R7/R9); block-end
//    atomics must be ADDRESS-SPREAD (R25: 1024 same-address = +7us).
//  - __launch_bounds__(256,2) on chamfer (VGPR=128; cap-128 spills, R13).
//  - Neutral: 32x32x16, depth-8 ring, in-place ring+min3, swizzle gran.
// Accuracy: K=13 pack drops only lo.lo (~1e-5 << 1.26e-3 threshold).
//   A k: [-2sh(3), -2sl(3), -2sh(3), s2h, s2l, 1, 1, 0,0,0]
//   B k: [ th(3),   th(3),   tl(3),  1, 1, t2h, t2l, 0,0,0]
// 16x16x32 layouts (m89/m91): A[m=lane&15][k=(lane>>4)*8+j], B same
// (n=lane&15); D: col=lane&15, row=(lane>>4)*4+reg.
// Budget: ~40-48us harness d_ws re-poison (268MB fill, timed, drifts) +
// 2 kernel dispatches. Judge rounds by (total - fill).

#define NPTS 4096
#define NB   8

typedef __attribute__((ext_vector_type(8))) short bf16x8;
typedef __attribute__((ext_vector_type(4))) float floatx4;

// ws layout: Apack[srcs], Apack[tgts], Bpack[srcs], Bpack[tgts], slots(8KB)
#define OFF_APACK_S 0u
#define OFF_APACK_T (1u << 20)
#define OFF_BPACK_S (2u << 20)
#define OFF_BPACK_T (3u << 20)
#define OFF_SLOT    (4u << 20)

union V16 { int4 i; bf16x8 h; };

__device__ __forceinline__ unsigned short f2bf(float f) {
    unsigned u = __float_as_uint(f);
    u += 0x7FFFu + ((u >> 16) & 1u);       // RNE
    return (unsigned short)(u >> 16);
}
__device__ __forceinline__ float bf2f(unsigned short h) {
    return __uint_as_float(((unsigned)h) << 16);
}
__device__ __forceinline__ int pk(unsigned short lo, unsigned short hi) {
    return (int)((unsigned)lo | ((unsigned)hi << 16));
}

// ---------------- Kernel 1: pack A-style + B-style, 1 point/thread --------
__device__ __forceinline__ void pack_point(const float* __restrict__ cloud,
                                           int b, int j, int gid,
                                           char* __restrict__ apack,
                                           char* __restrict__ bpack) {
    const unsigned short ONE = 0x3F80;
    const float* p = cloud + b * 3 * NPTS;
    const float x = p[j], y = p[NPTS + j], z = p[2 * NPTS + j];
    const unsigned short hx = f2bf(x), hy = f2bf(y), hz = f2bf(z);
    const unsigned short lx = f2bf(x - bf2f(hx));
    const unsigned short ly = f2bf(y - bf2f(hy));
    const unsigned short lz = f2bf(z - bf2f(hz));
    const unsigned short a0 = f2bf(-2.0f * bf2f(hx));
    const unsigned short a1 = f2bf(-2.0f * bf2f(hy));
    const unsigned short a2 = f2bf(-2.0f * bf2f(hz));
    const unsigned short m0 = f2bf(-2.0f * (x - bf2f(hx)));
    const unsigned short m1 = f2bf(-2.0f * (y - bf2f(hy)));
    const unsigned short m2 = f2bf(-2.0f * (z - bf2f(hz)));
    const float n2 = fmaf(z, z, fmaf(y, y, x * x));
    const unsigned short n2h = f2bf(n2);
    const unsigned short n2l = f2bf(n2 - bf2f(n2h));

    int4* Ap = (int4*)(apack + (size_t)gid * 32);
    Ap[0] = make_int4(pk(a0, a1), pk(a2, m0), pk(m1, m2), pk(a0, a1));
    Ap[1] = make_int4(pk(a2, n2h), pk(n2l, ONE), pk(ONE, 0), 0);

    int4* Bp = (int4*)(bpack + (size_t)gid * 32);
    Bp[0] = make_int4(pk(hx, hy), pk(hz, hx), pk(hy, hz), pk(lx, ly));
    Bp[1] = make_int4(pk(lz, ONE), pk(ONE, n2h), pk(n2l, 0), 0);
}

__global__ __launch_bounds__(256)
void transform_kernel(const float* __restrict__ srcs,
                      const float* __restrict__ tgts,
                      char* __restrict__ ws,
                      float* __restrict__ out) {
    const int gid = blockIdx.x * 256 + threadIdx.x;   // 0..65535
    if (gid == 0) out[0] = 0.0f;          // accumulator for slot finalizers
    if (gid < 2048)                       // zero 8KB slot region (poisoned)
        ((int*)(ws + OFF_SLOT))[gid] = 0;
    const int dir = gid >> 15;
    const int rem = gid & 32767;                      // b*4096 + j
    const int b = rem >> 12, j = rem & 4095;
    if (dir == 0)
        pack_point(srcs, b, j, rem, ws + OFF_APACK_S, ws + OFF_BPACK_S);
    else
        pack_point(tgts, b, j, rem, ws + OFF_APACK_T, ws + OFF_BPACK_T);
}

// ---------------- Kernel 2: row-min MFMA chamfer (16x16x32, 64 rows) ------
__global__ __launch_bounds__(256, 2)
void chamfer_kernel(char* __restrict__ ws, float* __restrict__ out) {
    const int blk    = blockIdx.x;        // 0..1023
    const int group  = blk & 15;          // XCD-aware swizzle
    const int dir    = group >> 3;
    const int b      = group & 7;
    const int stripe = blk >> 4;          // 0..63, 64 query rows each
    const int tid    = threadIdx.x;
    const int wave   = tid >> 6;          // 0..3
    const int lane   = tid & 63;
    const int l15    = lane & 15;
    const int quad   = lane >> 4;         // k-half = (quad&1)*16 bytes

    const char* Ap = ws + (dir == 0 ? OFF_APACK_S : OFF_APACK_T);
    const char* Bp = ws + (dir == 0 ? OFF_BPACK_T : OFF_BPACK_S);

    // 4 row-tiles of 16 rows; quads 2,3 replicate quads 0,1 -> D = 2P.
    V16 av[4];
#pragma unroll
    for (int rt = 0; rt < 4; rt++)
        av[rt].i = *(const int4*)(Ap +
            (size_t)(b * NPTS + stripe * 64 + rt * 16 + l15) * 32 + (quad & 1) * 16);

    floatx4 rmin[4];
#pragma unroll
    for (int rt = 0; rt < 4; rt++)
        rmin[rt] = (floatx4){3.0e38f, 3.0e38f, 3.0e38f, 3.0e38f};
    const floatx4 zero = {0.0f, 0.0f, 0.0f, 0.0f};

    const int ct0 = wave * 64;            // 64 col-tiles (of 16 pts) per wave
    const char* bbase = Bp + (size_t)(b * NPTS + ct0 * 16 + l15) * 32 + (quad & 1) * 16;

    // depth-4 register prefetch ring over 64 tiles, 512 B apart; wrap &63
    V16 t0, t1, t2, t3;
    t0.i = *(const int4*)(bbase);
    t1.i = *(const int4*)(bbase + 512);
    t2.i = *(const int4*)(bbase + 1024);
    t3.i = *(const int4*)(bbase + 1536);

#pragma unroll
    for (int i = 0; i < 64; i += 4) {
        V16 n0, n1, n2, n3;
        n0.i = *(const int4*)(bbase + (size_t)((i + 4) & 63) * 512);
        n1.i = *(const int4*)(bbase + (size_t)((i + 5) & 63) * 512);
        n2.i = *(const int4*)(bbase + (size_t)((i + 6) & 63) * 512);
        n3.i = *(const int4*)(bbase + (size_t)((i + 7) & 63) * 512);
#pragma unroll
        for (int u = 0; u < 4; u++) {
            const bf16x8 bf = (u == 0 ? t0.h : u == 1 ? t1.h : u == 2 ? t2.h : t3.h);
#pragma unroll
            for (int rt = 0; rt < 4; rt++) {
                const floatx4 d =
                    __builtin_amdgcn_mfma_f32_16x16x32_bf16(av[rt].h, bf, zero, 0, 0, 0);
#pragma unroll
                for (int r = 0; r < 4; r++)
                    rmin[rt][r] = fminf(rmin[rt][r], d[r]);
            }
        }
        t0 = n0; t1 = n1; t2 = n2; t3 = n3;
    }

    // ---- butterfly min over the 16 col-lanes ----
#pragma unroll
    for (int off = 1; off < 16; off <<= 1) {
#pragma unroll
        for (int rt = 0; rt < 4; rt++)
#pragma unroll
            for (int r = 0; r < 4; r++)
                rmin[rt][r] = fminf(rmin[rt][r], __shfl_xor(rmin[rt][r], off, 64));
    }
    // quad leader holds rows rt*16 + quad*4 + r
    __shared__ float sRow[4][64];
    if (l15 == 0) {
#pragma unroll
        for (int rt = 0; rt < 4; rt++)
#pragma unroll
            for (int r = 0; r < 4; r++)
                sRow[wave][rt * 16 + quad * 4 + r] = rmin[rt][r];
    }
    __syncthreads();
    if (tid < 64) {
        float m = fminf(fminf(sRow[0][tid], sRow[1][tid]),
                        fminf(sRow[2][tid], sRow[3][tid]));
        m = fmaxf(m * 0.5f, 0.0f);        // undo K-replication doubling
        float g = m / (m + 1.0f);         // GM, MU=1
#pragma unroll
        for (int off = 1; off < 64; off <<= 1)
            g += __shfl_xor(g, off, 64);
        if (tid == 0) {
            // two-level slot reduction: 16 blocks/slot, 64 slots in
            // separate 128B lines -> parallel L2 channels (R25 lesson:
            // 1024 same-address atomics = ~13us serialized tail).
            const int s = blk & 63;
            float* slotSum = (float*)(ws + OFF_SLOT + (size_t)s * 128);
            int*   slotCnt = (int*)(slotSum + 1);
            const float gp = g * (1.0f / (NB * NPTS));
            const float old = atomicAdd(slotSum, gp);
            // data-dep on 'old' orders cnt-add after sum-add completion
            const int oc = atomicAdd(slotCnt, 1 + (int)(old * 0.0f));
            if (oc == 15) {               // 16th arrival: all sums applied
                const float tot = atomicAdd(slotSum, 0.0f);  // atomic read
                atomicAdd(out, tot);      // 64 total atomics on out[0]
            }
        }
    }
}

extern "C" void kernel_launch(void* const* d_in, const int* in_sizes, int n_in,
                              void* d_out, int out_size, void* d_ws, size_t ws_size,
                              hipStream_t stream) {
    const float* srcs = (const float*)d_in[0];
    const float* tgts = (const float*)d_in[1];
    float* out = (float*)d_out;
    char* ws = (char*)d_ws;

    transform_kernel<<<dim3(256), dim3(256), 0, stream>>>(srcs, tgts, ws, out);
    chamfer_kernel<<<dim3(1024), dim3(256), 0, stream>>>(ws, out);
}

// Round 9
// 72.686 us; speedup vs baseline: 1.3017x; 1.0310x over previous
//
#include <hip/hip_runtime.h>

// GMLoss: bidirectional chamfer min + Geman-McClure penalty (MU=1).
// srcs, tgts: [B=8, D=3, N=4096] fp32. Output: scalar fp32.
//
// FINAL = R14 exact revert (harness-verified best: 72.6us this session,
// 73.0us prior session). R19-R26 explored three structural families beyond
// this; all measured worse or neutral:
//   - single-pass bidirectional (halved MFMA work): best 82.5us. The col-min
//     consumer chain forces either scratch spill (full unroll: 600MB traffic,
//     245us) or latency serialization (unroll 1: +7us vs two-pass).
//   - occupancy-doubled row-split (32 rows, (256,4)): 94.6us -- duplicated
//     per-tile overhead + in-loop flush regression.
//   - dispatch fusion via block-end atomics: same-address atomics serialize
//     (~13us tail, R25); 64-slot spread fixes the tail (R26: 74.9us) but
//     nets +2us vs the separate finish kernel. Dispatch overhead ~2-3us,
//     not the ~7us hypothesized.
// Conclusion: rest-after-fill plateaus at ~32us across 4 orthogonal
// families; fill (268MB harness re-poison, timed) runs at 82-84% of
// achievable HBM BW. This structure is the measured optimum.
//
// Structure and why (18 rounds of the prior session):
//  - transform: fp32 -> K=13 hi/lo bf16 MFMA packing for both clouds
//    (A-style + B-style), 1 point/thread.
//  - chamfer: 16x16x32 bf16 MFMA, K-replication (quads 2,3 re-read bytes
//    0..31 -> D=2P, halve after min), 64 query rows/block, depth-4 register
//    prefetch ring, XCD swizzle group=blk&15, per-block GM partials via
//    PLAIN STORES to bsum.
//  - finish: 1-block reduce of bsum -> scalar.
// Hard-won constraints (counter-evidenced):
//  - NO device-scope fences or bulk atomics in hot kernels (R7: 2M atomicMin
//    -> 478MB RMW traffic, 263us; R9: per-block __threadfence -> 70us floor;
//    R25: 1024 same-address block-end atomics -> +7us).
//  - __launch_bounds__(256,2): cap-128 squeezes spill scratch (R13: VGPR=64,
//    WRITE 244MB, 159us); floatx16 accs at low caps get AGPR-exiled (R12).
//  - MFMA results must have SHORT consumer chains under full unroll
//    (R19/R20: adding a serial col-min chain -> 3.1KB/thread spill).
//  - Neutral when tested around this structure: 32x32x16 shape (R15),
//    depth-8 ring + (256,4) (R16), in-place ring + min3 (R17), XCD swizzle
//    granularity (R10/R11), single-pass & fusion families (R19-R26).
// Accuracy: K=13 pack gives |s|^2+|t|^2-2s.t with only sl.tl dropped
// (~1e-5 << 1.26e-3 threshold); absmax 0.0 on every passing round.
//   A k: [-2sh(3), -2sl(3), -2sh(3), s2h, s2l, 1, 1, 0,0,0]
//   B k: [ th(3),   th(3),   tl(3),  1, 1, t2h, t2l, 0,0,0]
// 16x16x32 layouts (m89/m91): A[m=lane&15][k=(lane>>4)*8+j], B same
// (n=lane&15); D: col=lane&15, row=(lane>>4)*4+reg.
// Budget at ceiling: ~40.5us harness d_ws re-poison (268MB fill, timed,
// drifts +-3us) + ~32us kernels; kernel portion plateaued across all
// structural families tried (two-pass tweaks, single-pass, fusion).

#define NPTS 4096
#define NB   8

typedef __attribute__((ext_vector_type(8))) short bf16x8;
typedef __attribute__((ext_vector_type(4))) float floatx4;

// ws layout: Apack[srcs], Apack[tgts], Bpack[srcs], Bpack[tgts], bsum[1024]
#define OFF_APACK_S 0u
#define OFF_APACK_T (1u << 20)
#define OFF_BPACK_S (2u << 20)
#define OFF_BPACK_T (3u << 20)
#define OFF_BSUM    (4u << 20)

union V16 { int4 i; bf16x8 h; };

__device__ __forceinline__ unsigned short f2bf(float f) {
    unsigned u = __float_as_uint(f);
    u += 0x7FFFu + ((u >> 16) & 1u);       // RNE
    return (unsigned short)(u >> 16);
}
__device__ __forceinline__ float bf2f(unsigned short h) {
    return __uint_as_float(((unsigned)h) << 16);
}
__device__ __forceinline__ int pk(unsigned short lo, unsigned short hi) {
    return (int)((unsigned)lo | ((unsigned)hi << 16));
}

// ---------------- Kernel 1: pack A-style + B-style, 1 point/thread --------
__device__ __forceinline__ void pack_point(const float* __restrict__ cloud,
                                           int b, int j, int gid,
                                           char* __restrict__ apack,
                                           char* __restrict__ bpack) {
    const unsigned short ONE = 0x3F80;
    const float* p = cloud + b * 3 * NPTS;
    const float x = p[j], y = p[NPTS + j], z = p[2 * NPTS + j];
    const unsigned short hx = f2bf(x), hy = f2bf(y), hz = f2bf(z);
    const unsigned short lx = f2bf(x - bf2f(hx));
    const unsigned short ly = f2bf(y - bf2f(hy));
    const unsigned short lz = f2bf(z - bf2f(hz));
    const unsigned short a0 = f2bf(-2.0f * bf2f(hx));
    const unsigned short a1 = f2bf(-2.0f * bf2f(hy));
    const unsigned short a2 = f2bf(-2.0f * bf2f(hz));
    const unsigned short m0 = f2bf(-2.0f * (x - bf2f(hx)));
    const unsigned short m1 = f2bf(-2.0f * (y - bf2f(hy)));
    const unsigned short m2 = f2bf(-2.0f * (z - bf2f(hz)));
    const float n2 = fmaf(z, z, fmaf(y, y, x * x));
    const unsigned short n2h = f2bf(n2);
    const unsigned short n2l = f2bf(n2 - bf2f(n2h));

    int4* Ap = (int4*)(apack + (size_t)gid * 32);
    Ap[0] = make_int4(pk(a0, a1), pk(a2, m0), pk(m1, m2), pk(a0, a1));
    Ap[1] = make_int4(pk(a2, n2h), pk(n2l, ONE), pk(ONE, 0), 0);

    int4* Bp = (int4*)(bpack + (size_t)gid * 32);
    Bp[0] = make_int4(pk(hx, hy), pk(hz, hx), pk(hy, hz), pk(lx, ly));
    Bp[1] = make_int4(pk(lz, ONE), pk(ONE, n2h), pk(n2l, 0), 0);
}

__global__ __launch_bounds__(256)
void transform_kernel(const float* __restrict__ srcs,
                      const float* __restrict__ tgts,
                      char* __restrict__ ws) {
    const int gid = blockIdx.x * 256 + threadIdx.x;   // 0..65535
    const int dir = gid >> 15;
    const int rem = gid & 32767;                      // b*4096 + j
    const int b = rem >> 12, j = rem & 4095;
    if (dir == 0)
        pack_point(srcs, b, j, rem, ws + OFF_APACK_S, ws + OFF_BPACK_S);
    else
        pack_point(tgts, b, j, rem, ws + OFF_APACK_T, ws + OFF_BPACK_T);
}

// ---------------- Kernel 2: row-min MFMA chamfer (16x16x32, 64 rows) ------
__global__ __launch_bounds__(256, 2)
void chamfer_kernel(char* __restrict__ ws) {
    const int blk    = blockIdx.x;        // 0..1023
    const int group  = blk & 15;          // XCD-aware swizzle
    const int dir    = group >> 3;
    const int b      = group & 7;
    const int stripe = blk >> 4;          // 0..63, 64 query rows each
    const int tid    = threadIdx.x;
    const int wave   = tid >> 6;          // 0..3
    const int lane   = tid & 63;
    const int l15    = lane & 15;
    const int quad   = lane >> 4;         // k-half = (quad&1)*16 bytes

    const char* Ap = ws + (dir == 0 ? OFF_APACK_S : OFF_APACK_T);
    const char* Bp = ws + (dir == 0 ? OFF_BPACK_T : OFF_BPACK_S);

    // 4 row-tiles of 16 rows; quads 2,3 replicate quads 0,1 -> D = 2P.
    V16 av[4];
#pragma unroll
    for (int rt = 0; rt < 4; rt++)
        av[rt].i = *(const int4*)(Ap +
            (size_t)(b * NPTS + stripe * 64 + rt * 16 + l15) * 32 + (quad & 1) * 16);

    floatx4 rmin[4];
#pragma unroll
    for (int rt = 0; rt < 4; rt++)
        rmin[rt] = (floatx4){3.0e38f, 3.0e38f, 3.0e38f, 3.0e38f};
    const floatx4 zero = {0.0f, 0.0f, 0.0f, 0.0f};

    const int ct0 = wave * 64;            // 64 col-tiles (of 16 pts) per wave
    const char* bbase = Bp + (size_t)(b * NPTS + ct0 * 16 + l15) * 32 + (quad & 1) * 16;

    // depth-4 register prefetch ring over 64 tiles, 512 B apart; wrap &63
    V16 t0, t1, t2, t3;
    t0.i = *(const int4*)(bbase);
    t1.i = *(const int4*)(bbase + 512);
    t2.i = *(const int4*)(bbase + 1024);
    t3.i = *(const int4*)(bbase + 1536);

#pragma unroll
    for (int i = 0; i < 64; i += 4) {
        V16 n0, n1, n2, n3;
        n0.i = *(const int4*)(bbase + (size_t)((i + 4) & 63) * 512);
        n1.i = *(const int4*)(bbase + (size_t)((i + 5) & 63) * 512);
        n2.i = *(const int4*)(bbase + (size_t)((i + 6) & 63) * 512);
        n3.i = *(const int4*)(bbase + (size_t)((i + 7) & 63) * 512);
#pragma unroll
        for (int u = 0; u < 4; u++) {
            const bf16x8 bf = (u == 0 ? t0.h : u == 1 ? t1.h : u == 2 ? t2.h : t3.h);
#pragma unroll
            for (int rt = 0; rt < 4; rt++) {
                const floatx4 d =
                    __builtin_amdgcn_mfma_f32_16x16x32_bf16(av[rt].h, bf, zero, 0, 0, 0);
#pragma unroll
                for (int r = 0; r < 4; r++)
                    rmin[rt][r] = fminf(rmin[rt][r], d[r]);
            }
        }
        t0 = n0; t1 = n1; t2 = n2; t3 = n3;
    }

    // ---- butterfly min over the 16 col-lanes ----
#pragma unroll
    for (int off = 1; off < 16; off <<= 1) {
#pragma unroll
        for (int rt = 0; rt < 4; rt++)
#pragma unroll
            for (int r = 0; r < 4; r++)
                rmin[rt][r] = fminf(rmin[rt][r], __shfl_xor(rmin[rt][r], off, 64));
    }
    // quad leader holds rows rt*16 + quad*4 + r
    __shared__ float sRow[4][64];
    if (l15 == 0) {
#pragma unroll
        for (int rt = 0; rt < 4; rt++)
#pragma unroll
            for (int r = 0; r < 4; r++)
                sRow[wave][rt * 16 + quad * 4 + r] = rmin[rt][r];
    }
    __syncthreads();
    if (tid < 64) {
        float m = fminf(fminf(sRow[0][tid], sRow[1][tid]),
                        fminf(sRow[2][tid], sRow[3][tid]));
        m = fmaxf(m * 0.5f, 0.0f);        // undo K-replication doubling
        float g = m / (m + 1.0f);         // GM, MU=1
#pragma unroll
        for (int off = 1; off < 64; off <<= 1)
            g += __shfl_xor(g, off, 64);
        if (tid == 0)
            ((float*)(ws + OFF_BSUM))[blk] = g;   // plain store
    }
}

// ---------------- Kernel 3: single-block finish ----------------
__global__ __launch_bounds__(256)
void finish_kernel(const char* __restrict__ ws, float* __restrict__ out) {
    const float* bsum = (const float*)(ws + OFF_BSUM);
    const int tid = threadIdx.x;
    float g = bsum[tid] + bsum[tid + 256] + bsum[tid + 512] + bsum[tid + 768];
#pragma unroll
    for (int off = 1; off < 64; off <<= 1)
        g += __shfl_xor(g, off, 64);
    __shared__ float sp[4];
    if ((tid & 63) == 0) sp[tid >> 6] = g;
    __syncthreads();
    if (tid == 0)
        out[0] = (sp[0] + sp[1] + sp[2] + sp[3]) * (1.0f / (NB * NPTS));
}

extern "C" void kernel_launch(void* const* d_in, const int* in_sizes, int n_in,
                              void* d_out, int out_size, void* d_ws, size_t ws_size,
                              hipStream_t stream) {
    const float* srcs = (const float*)d_in[0];
    const float* tgts = (const float*)d_in[1];
    float* out = (float*)d_out;
    char* ws = (char*)d_ws;

    transform_kernel<<<dim3(256), dim3(256), 0, stream>>>(srcs, tgts, ws);
    chamfer_kernel<<<dim3(1024), dim3(256), 0, stream>>>(ws);
    finish_kernel<<<dim3(1), dim3(256), 0, stream>>>(ws, out);
}